// Round 2
// baseline (76748.480 us; speedup 1.0000x reference)
//
#include <hip/hip_runtime.h>

typedef unsigned int u32;
typedef unsigned short u16;
typedef _Float16 f16;
typedef _Float16 f16x2 __attribute__((ext_vector_type(2)));

#define T_SEQ 32768

// ---------------- ws layout (bytes) ----------------
static const size_t OFF_DT   = 0;         // u32 dtype flag (1 = f32 inputs)
static const size_t OFF_FLG  = 1024;      // u32[128] (legacy, kept zeroed)
static const size_t OFF_MAP  = 4096;      // int [T]
static const size_t OFF_H1G  = 135168;    // f16 [1024][512]
static const size_t OFF_BIAS = 1183744;   // f32 [4][1024]
static const size_t OFF_FCW  = 1200128;   // f32 [512*64]
static const size_t OFF_WQ8  = 1331200;   // u32 [4][1024][64] int8 W_hh (1 MB)
static const size_t OFF_WIH0 = 3428352;   // u32 [2][1024][32]
static const size_t OFF_WIH1 = 3690496;   // u32 [2][1024][256]
static const size_t OFF_XQ   = 5787648;   // u32 [T][32]
static const size_t OFF_H0   = 9981952;   // f16 [T][512]
static const size_t OFF_XG   = 43536384;  // f16 [ndir][T][1024], LAST (adaptive)
static const size_t XG_DIR   = (size_t)T_SEQ * 1024 * 2;  // 67108864 bytes
static const size_t NEED_PAR = OFF_XG + 2 * XG_DIR;       // 177754112

// ---------------- helpers ----------------
__device__ __forceinline__ float bf2f(u16 u) {
  union { u32 i; float f; } v; v.i = ((u32)u) << 16; return v.f;
}
__device__ __forceinline__ u16 f2bf(float f) {
  union { float f; u32 i; } v; v.f = f;
  u32 u = v.i;
  return (u16)((u + 0x7fffu + ((u >> 16) & 1u)) >> 16);
}
__device__ __forceinline__ u32 packf2(float a, float b) {
  f16x2 p; p.x = (f16)a; p.y = (f16)b;
  return __builtin_bit_cast(u32, p);
}
__device__ __forceinline__ u32 bf2f2(u32 v) {  // two bf16 -> two f16
  union { u32 i; float f; } lo, hi;
  lo.i = v << 16; hi.i = v & 0xffff0000u;
  return packf2(lo.f, hi.f);
}
__device__ __forceinline__ float ldf(const void* p, size_t i, u32 isf) {
  return isf ? ((const float*)p)[i] : bf2f(((const u16*)p)[i]);
}
__device__ __forceinline__ float fdot2f(f16x2 a, f16x2 b, float c) {
#if __has_builtin(__builtin_amdgcn_fdot2)
  return __builtin_amdgcn_fdot2(a, b, c, false);
#else
  return c + (float)a.x * (float)b.x + (float)a.y * (float)b.y;
#endif
}
__device__ __forceinline__ float fdotu(u32 a, u32 b, float c) {
  return fdot2f(__builtin_bit_cast(f16x2, a), __builtin_bit_cast(f16x2, b), c);
}
__device__ __forceinline__ int sdot4(u32 a, u32 b, int c) {
#if __has_builtin(__builtin_amdgcn_sdot4)
  return __builtin_amdgcn_sdot4((int)a, (int)b, c, false);
#else
  int r = c;
#pragma unroll
  for (int j = 0; j < 4; ++j)
    r += (int)(signed char)(a >> (8 * j)) * (int)(signed char)(b >> (8 * j));
  return r;
#endif
}
// quad lane permutes via DPP — pure VALU, no LDS pipe.
__device__ __forceinline__ int dpp_xor1(int x) {  // quad_perm [1,0,3,2]
#if __has_builtin(__builtin_amdgcn_update_dpp)
  return __builtin_amdgcn_update_dpp(0, x, 0xB1, 0xF, 0xF, true);
#else
  return __shfl_xor(x, 1);
#endif
}
__device__ __forceinline__ int dpp_xor2(int x) {  // quad_perm [2,3,0,1]
#if __has_builtin(__builtin_amdgcn_update_dpp)
  return __builtin_amdgcn_update_dpp(0, x, 0x4E, 0xF, 0xF, true);
#else
  return __shfl_xor(x, 2);
#endif
}
__device__ __forceinline__ float sigf(float x) {
  return __builtin_amdgcn_rcpf(1.0f + __builtin_amdgcn_exp2f(-1.4426950408889634f * x));
}
__device__ __forceinline__ float tanhf_fast(float x) {
  return 1.0f - 2.0f * __builtin_amdgcn_rcpf(1.0f + __builtin_amdgcn_exp2f(2.8853900817779268f * x));
}

// ---------------- dtype detection ----------------
__global__ void k_detect(const u16* __restrict__ probe, u32* __restrict__ dt) {
  __shared__ int cnt;
  if (threadIdx.x == 0) cnt = 0;
  __syncthreads();
  int bad = 0;
  for (int i = threadIdx.x; i < 8192; i += 256) {
    float v = bf2f(probe[i]);
    if (!(v * v <= 16.0f)) bad++;
  }
  atomicAdd(&cnt, bad);
  __syncthreads();
  if (threadIdx.x == 0) *dt = (cnt > 64) ? 1u : 0u;
}

// ---------------- conversions ----------------
__global__ void k_conv_pairs(const void* __restrict__ src, u32* __restrict__ dst,
                             int np, const u32* __restrict__ dtp) {
  u32 isf = *dtp;
  int i = blockIdx.x * 256 + threadIdx.x;
  if (i >= np) return;
  if (isf) {
    const float* s = (const float*)src;
    dst[i] = packf2(s[2 * i], s[2 * i + 1]);
  } else {
    dst[i] = bf2f2(((const u32*)src)[i]);
  }
}

// int8-quantize one W_hh matrix [1024][256] -> u32 [1024][64], scale 2048
__global__ void k_quant(const void* __restrict__ src, u32* __restrict__ dst,
                        const u32* __restrict__ dtp) {
  u32 isf = *dtp;
  int i = blockIdx.x * 256 + threadIdx.x;  // 65536
  int row = i >> 6, c = i & 63;
  u32 out = 0;
#pragma unroll
  for (int j = 0; j < 4; ++j) {
    float w = ldf(src, (size_t)row * 256 + 4 * c + j, isf);
    int q = (int)rintf(w * 2048.0f);
    q = q > 127 ? 127 : (q < -127 ? -127 : q);
    out |= ((u32)(q & 0xff)) << (8 * j);
  }
  dst[i] = out;
}

__global__ void k_conv_misc(const void* bi0f, const void* bh0f, const void* bi0b, const void* bh0b,
                            const void* bi1f, const void* bh1f, const void* bi1b, const void* bh1b,
                            const void* fcb, float* __restrict__ bias, float* __restrict__ fcw,
                            u32* __restrict__ flags, int* __restrict__ map,
                            const u32* __restrict__ dtp) {
  u32 isf = *dtp;
  int i = blockIdx.x * 256 + threadIdx.x;
  if (i < 4096) {
    int ld = i >> 10, r = i & 1023;
    const void* bi; const void* bh;
    if (ld == 0)      { bi = bi0f; bh = bh0f; }
    else if (ld == 1) { bi = bi0b; bh = bh0b; }
    else if (ld == 2) { bi = bi1f; bh = bh1f; }
    else              { bi = bi1b; bh = bh1b; }
    bias[i] = ldf(bi, r, isf) + ldf(bh, r, isf);
  } else if (i < 36864) {
    fcw[i - 4096] = ldf(fcb, i - 4096, isf);
  } else if (i < 36992) {
    flags[i - 36864] = 0;
  } else if (i < 69760) {
    map[i - 36992] = -1;
  }
}

__global__ void k_conv_x(const void* __restrict__ Y, const void* __restrict__ dT,
                         u32* __restrict__ xq, const u32* __restrict__ dtp) {
  u32 isf = *dtp;
  int i = blockIdx.x * 256 + threadIdx.x;  // T*32
  if (i >= T_SEQ * 32) return;
  int t = i >> 5, m = i & 31, k2 = 2 * m;
  float a = ldf(Y, (size_t)t * 63 + k2, isf);
  float b = (k2 + 1 < 63) ? ldf(Y, (size_t)t * 63 + k2 + 1, isf) : ldf(dT, t, isf);
  xq[i] = packf2(a, b);
}

__global__ void k_map_set(const int* __restrict__ idx, int* __restrict__ map) {
  int i = blockIdx.x * 256 + threadIdx.x;
  if (i < 1024) map[idx[i]] = i;
}

// ---------------- input-projection GEMM ----------------
__global__ __launch_bounds__(256) void k_gemm(
    const u32* __restrict__ Aq, const u32* __restrict__ Wc,
    const float* __restrict__ bias, f16* __restrict__ xg_slot, int Kp) {
  int t0 = blockIdx.x << 6, r0 = blockIdx.y << 6;
  int tid = threadIdx.x, tx = tid & 15, ty = tid >> 4;
  __shared__ u32 As[64][33];
  __shared__ u32 Bs[64][33];
  float acc[4][4] = {};
  for (int kp0 = 0; kp0 < Kp; kp0 += 32) {
#pragma unroll
    for (int i = 0; i < 8; ++i) {
      int idx = tid + (i << 8);
      int row = idx >> 5, kp = idx & 31, kpg = kp0 + kp;
      As[row][kp] = Aq[(size_t)(t0 + row) * Kp + kpg];
      Bs[row][kp] = Wc[(size_t)(r0 + row) * Kp + kpg];
    }
    __syncthreads();
#pragma unroll 4
    for (int kk = 0; kk < 32; ++kk) {
      u32 av[4], bv[4];
#pragma unroll
      for (int i = 0; i < 4; ++i) av[i] = As[ty * 4 + i][kk];
#pragma unroll
      for (int i = 0; i < 4; ++i) bv[i] = Bs[tx * 4 + i][kk];
#pragma unroll
      for (int i = 0; i < 4; ++i)
#pragma unroll
        for (int j = 0; j < 4; ++j)
          acc[i][j] = fdotu(av[i], bv[j], acc[i][j]);
    }
    __syncthreads();
  }
#pragma unroll
  for (int i = 0; i < 4; ++i) {
    int t = t0 + ty * 4 + i;
#pragma unroll
    for (int j = 0; j < 4; ++j) {
      int r = r0 + tx * 4 + j;
      xg_slot[(size_t)t * 1024 + r] = (f16)(acc[i][j] + bias[r]);
    }
  }
}

// ---------------- recurrence: int8 weights, ONE workgroup per direction ------
// 1024 threads. Thread = (unit u = tid>>2, K-quarter qq = tid&3):
//   owns 4 gate rows (u, 256+u, 512+u, 768+u), K in [64*qq, 64*qq+64).
// Weights: 4 gates x 16 u32 = 64 VGPRs/thread. A 1024-thread WG forces a
// HARD <=128 VGPR/wave budget (16 waves must fit the 512-reg SIMD file), so
// the allocator has NO slack to demote the weight array to AGPRs (the round-1
// failure: VGPR_Count=84 with 128 pinned dwords => weights sat in AGPRs with
// per-use v_accvgpr_read on the critical loop). Live set ~105 regs: fits.
// K-quarters combine with 2 exact-integer DPP quad-perm adds; all 4 lanes of
// a quad redundantly compute the activations (no LDS gate exchange, no
// divergence), leader lane (qq==0) writes h. One barrier/step, double-buffered
// 256B h-buffer; ds_read_b128 h loads are 16-lane broadcast, 2-way bank alias
// (free per m136).
__global__ __launch_bounds__(1024, 4) void k_recur2(
    const f16* __restrict__ xg, const u32* __restrict__ wq,
    f16* __restrict__ h_full, f16* __restrict__ h1g,
    const int* __restrict__ map, int dir0) {
  const int dir = dir0 + blockIdx.x;
  const int tid = threadIdx.x;
  const int u = tid >> 2;    // hidden unit owned by this quad
  const int qq = tid & 3;    // K quarter
  const u32* wqd = wq + ((size_t)dir << 16);  // [1024][64]

  __shared__ __align__(16) unsigned char hb8[2][256];  // double-buffered h (i8)

  u32 w0[16], w1[16], w2[16], w3[16];
  {
    const uint4* pw = (const uint4*)wqd;  // row stride = 16 uint4
    const int b0 = ((0 << 8) | u) * 16 + (qq << 2);
    const int b1 = ((1 << 8) | u) * 16 + (qq << 2);
    const int b2 = ((2 << 8) | u) * 16 + (qq << 2);
    const int b3 = ((3 << 8) | u) * 16 + (qq << 2);
#pragma unroll
    for (int i = 0; i < 4; ++i) {
      uint4 v0 = pw[b0 + i]; uint4 v1 = pw[b1 + i];
      uint4 v2 = pw[b2 + i]; uint4 v3 = pw[b3 + i];
      w0[4 * i] = v0.x; w0[4 * i + 1] = v0.y; w0[4 * i + 2] = v0.z; w0[4 * i + 3] = v0.w;
      w1[4 * i] = v1.x; w1[4 * i + 1] = v1.y; w1[4 * i + 2] = v1.z; w1[4 * i + 3] = v1.w;
      w2[4 * i] = v2.x; w2[4 * i + 1] = v2.y; w2[4 * i + 2] = v2.z; w2[4 * i + 3] = v2.w;
      w3[4 * i] = v3.x; w3[4 * i + 1] = v3.y; w3[4 * i + 2] = v3.z; w3[4 * i + 3] = v3.w;
    }
  }
  // Pin weights in arch VGPRs.
#pragma unroll
  for (int i = 0; i < 16; ++i)
    asm volatile("" : "+v"(w0[i]), "+v"(w1[i]), "+v"(w2[i]), "+v"(w3[i]));

  if (tid < 128) ((u32*)hb8)[tid] = 0;

  float c_state = 0.f;
  const f16* xg_d = xg + ((size_t)blockIdx.x * T_SEQ * 1024);
  const float ksc = 1.0f / (2048.0f * 127.0f);

  int t = dir ? (T_SEQ - 1) : 0;
  float xa0 = (float)xg_d[(size_t)t * 1024 + u];
  float xa1 = (float)xg_d[(size_t)t * 1024 + 256 + u];
  float xa2 = (float)xg_d[(size_t)t * 1024 + 512 + u];
  float xa3 = (float)xg_d[(size_t)t * 1024 + 768 + u];
  int mp = map ? map[t] : -1;

  int p = 0;
  __syncthreads();  // hb8[0] zeroed

  for (int step = 0; step < T_SEQ; ++step) {
    float xb0 = xa0, xb1 = xa1, xb2 = xa2, xb3 = xa3;
    int ms = mp;
    const int tn = dir ? (T_SEQ - 2 - step) : (step + 1);
    if (step + 1 < T_SEQ) {  // prefetch next xg + map (wave-uniform branch)
      xa0 = (float)xg_d[(size_t)tn * 1024 + u];
      xa1 = (float)xg_d[(size_t)tn * 1024 + 256 + u];
      xa2 = (float)xg_d[(size_t)tn * 1024 + 512 + u];
      xa3 = (float)xg_d[(size_t)tn * 1024 + 768 + u];
      if (map) mp = map[tn];
    }
    int acc0 = 0, acc1 = 0, acc2 = 0, acc3 = 0;
    const uint4* hp = (const uint4*)(&hb8[p][qq << 6]);
    uint4 hv0 = hp[0], hv1 = hp[1], hv2 = hp[2], hv3 = hp[3];
#define DOT16(HV, B)                                   \
    acc0 = sdot4(w0[B],     HV.x, acc0);               \
    acc1 = sdot4(w1[B],     HV.x, acc1);               \
    acc2 = sdot4(w2[B],     HV.x, acc2);               \
    acc3 = sdot4(w3[B],     HV.x, acc3);               \
    acc0 = sdot4(w0[B + 1], HV.y, acc0);               \
    acc1 = sdot4(w1[B + 1], HV.y, acc1);               \
    acc2 = sdot4(w2[B + 1], HV.y, acc2);               \
    acc3 = sdot4(w3[B + 1], HV.y, acc3);               \
    acc0 = sdot4(w0[B + 2], HV.z, acc0);               \
    acc1 = sdot4(w1[B + 2], HV.z, acc1);               \
    acc2 = sdot4(w2[B + 2], HV.z, acc2);               \
    acc3 = sdot4(w3[B + 2], HV.z, acc3);               \
    acc0 = sdot4(w0[B + 3], HV.w, acc0);               \
    acc1 = sdot4(w1[B + 3], HV.w, acc1);               \
    acc2 = sdot4(w2[B + 3], HV.w, acc2);               \
    acc3 = sdot4(w3[B + 3], HV.w, acc3);
    DOT16(hv0, 0)
    DOT16(hv1, 4)
    DOT16(hv2, 8)
    DOT16(hv3, 12)
#undef DOT16
    // combine K-quarters across the quad (exact integer adds)
    acc0 += dpp_xor1(acc0); acc0 += dpp_xor2(acc0);
    acc1 += dpp_xor1(acc1); acc1 += dpp_xor2(acc1);
    acc2 += dpp_xor1(acc2); acc2 += dpp_xor2(acc2);
    acc3 += dpp_xor1(acc3); acc3 += dpp_xor2(acc3);
    float gi = sigf(xb0 + (float)acc0 * ksc);
    float gf = sigf(xb1 + (float)acc1 * ksc);
    float gg = tanhf_fast(xb2 + (float)acc2 * ksc);
    float go = sigf(xb3 + (float)acc3 * ksc);
    c_state = gf * c_state + gi * gg;
    float h = go * tanhf_fast(c_state);
    int q8 = (int)rintf(h * 127.0f);
    if (qq == 0) {
      hb8[p ^ 1][u] = (unsigned char)(q8 & 0xff);
      if (h_full) h_full[(size_t)t * 512 + (dir << 8) + u] = (f16)h;
      if (h1g && ms >= 0) h1g[(size_t)ms * 512 + (dir << 8) + u] = (f16)h;
    }
    __syncthreads();  // writes to hb8[p^1] visible; all reads of hb8[p] done
    p ^= 1;
    t = tn;
  }
}

// ---------------- FC + gather ----------------
__global__ void k_fc(const f16* __restrict__ h1g, const int* __restrict__ map,
                     const int* __restrict__ idx, const float* __restrict__ fcw,
                     void* __restrict__ out, const u32* __restrict__ dtp) {
  u32 isf = *dtp;
  int n = blockIdx.x;
  int cc = threadIdx.x;  // 64
  int slot = map[idx[n]];
  const f16* hp = h1g + (size_t)slot * 512;
  float acc = 0.f;
#pragma unroll 8
  for (int k = 0; k < 512; ++k) acc += (float)hp[k] * fcw[k * 64 + cc];
  int o = (cc < 32) ? (n * 32 + cc) : (32 * 1024 + n * 32 + (cc - 32));
  if (isf) ((float*)out)[o] = acc;
  else     ((u16*)out)[o]   = f2bf(acc);
}

// ---------------- launch ----------------
extern "C" void kernel_launch(void* const* d_in, const int* in_sizes, int n_in,
                              void* d_out, int out_size, void* d_ws, size_t ws_size,
                              hipStream_t stream) {
  const void* Y        = d_in[0];
  const void* dT       = d_in[1];
  const int*  idx      = (const int*)d_in[2];
  const void* w_ih_l0f = d_in[3];
  const void* w_hh_l0f = d_in[4];
  const void* b_ih_l0f = d_in[5];
  const void* b_hh_l0f = d_in[6];
  const void* w_ih_l0b = d_in[7];
  const void* w_hh_l0b = d_in[8];
  const void* b_ih_l0b = d_in[9];
  const void* b_hh_l0b = d_in[10];
  const void* w_ih_l1f = d_in[11];
  const void* w_hh_l1f = d_in[12];
  const void* b_ih_l1f = d_in[13];
  const void* b_hh_l1f = d_in[14];
  const void* w_ih_l1b = d_in[15];
  const void* w_hh_l1b = d_in[16];
  const void* b_ih_l1b = d_in[17];
  const void* b_hh_l1b = d_in[18];
  const void* fcbf     = d_in[19];

  char* ws = (char*)d_ws;
  u32*  dt    = (u32*)(ws + OFF_DT);
  u32*  flags = (u32*)(ws + OFF_FLG);
  int*  map   = (int*)(ws + OFF_MAP);
  f16*  h1g   = (f16*)(ws + OFF_H1G);
  float* bias = (float*)(ws + OFF_BIAS);
  float* fcw  = (float*)(ws + OFF_FCW);
  u32*  wq8   = (u32*)(ws + OFF_WQ8);
  u32*  wih0  = (u32*)(ws + OFF_WIH0);
  u32*  wih1  = (u32*)(ws + OFF_WIH1);
  u32*  xq    = (u32*)(ws + OFF_XQ);
  f16*  h0    = (f16*)(ws + OFF_H0);
  f16*  xg    = (f16*)(ws + OFF_XG);
  f16*  xg1   = xg + XG_DIR / 2;  // f16 elements

  const int par = (ws_size >= NEED_PAR) ? 1 : 0;

  k_detect<<<1, 256, 0, stream>>>((const u16*)w_hh_l0f, dt);
  k_quant<<<256, 256, 0, stream>>>(w_hh_l0f, wq8 + 0 * 65536, dt);
  k_quant<<<256, 256, 0, stream>>>(w_hh_l0b, wq8 + 1 * 65536, dt);
  k_quant<<<256, 256, 0, stream>>>(w_hh_l1f, wq8 + 2 * 65536, dt);
  k_quant<<<256, 256, 0, stream>>>(w_hh_l1b, wq8 + 3 * 65536, dt);
  k_conv_pairs<<<128, 256, 0, stream>>>(w_ih_l0f, wih0 + 0, 32768, dt);
  k_conv_pairs<<<128, 256, 0, stream>>>(w_ih_l0b, wih0 + 32768, 32768, dt);
  k_conv_pairs<<<1024, 256, 0, stream>>>(w_ih_l1f, wih1 + 0, 262144, dt);
  k_conv_pairs<<<1024, 256, 0, stream>>>(w_ih_l1b, wih1 + 262144, 262144, dt);
  k_conv_misc<<<273, 256, 0, stream>>>(b_ih_l0f, b_hh_l0f, b_ih_l0b, b_hh_l0b,
                                       b_ih_l1f, b_hh_l1f, b_ih_l1b, b_hh_l1b,
                                       fcbf, bias, fcw, flags, map, dt);
  k_conv_x<<<4096, 256, 0, stream>>>(Y, dT, xq, dt);
  k_map_set<<<4, 256, 0, stream>>>(idx, map);

  dim3 ggrid(T_SEQ / 64, 16);
  if (par) {
    k_gemm<<<ggrid, 256, 0, stream>>>(xq, wih0, bias, xg, 32);
    k_gemm<<<ggrid, 256, 0, stream>>>(xq, wih0 + 32768, bias + 1024, xg1, 32);
    k_recur2<<<2, 1024, 0, stream>>>(xg, wq8, h0, nullptr, nullptr, 0);
    k_gemm<<<ggrid, 256, 0, stream>>>((const u32*)h0, wih1, bias + 2048, xg, 256);
    k_gemm<<<ggrid, 256, 0, stream>>>((const u32*)h0, wih1 + 262144, bias + 3072, xg1, 256);
    k_recur2<<<2, 1024, 0, stream>>>(xg, wq8 + 2 * 65536, nullptr, h1g, map, 0);
  } else {
    k_gemm<<<ggrid, 256, 0, stream>>>(xq, wih0, bias, xg, 32);
    k_recur2<<<1, 1024, 0, stream>>>(xg, wq8, h0, nullptr, nullptr, 0);
    k_gemm<<<ggrid, 256, 0, stream>>>(xq, wih0 + 32768, bias + 1024, xg, 32);
    k_recur2<<<1, 1024, 0, stream>>>(xg, wq8, h0, nullptr, nullptr, 1);
    k_gemm<<<ggrid, 256, 0, stream>>>((const u32*)h0, wih1, bias + 2048, xg, 256);
    k_recur2<<<1, 1024, 0, stream>>>(xg, wq8 + 2 * 65536, nullptr, h1g, map, 0);
    k_gemm<<<ggrid, 256, 0, stream>>>((const u32*)h0, wih1 + 262144, bias + 3072, xg, 256);
    k_recur2<<<1, 1024, 0, stream>>>(xg, wq8 + 2 * 65536, nullptr, h1g, map, 1);
  }
  k_fc<<<1024, 64, 0, stream>>>(h1g, map, idx, fcw, d_out, dt);
}

// Round 3
// 56919.897 us; speedup vs baseline: 1.3484x; 1.3484x over previous
//
#include <hip/hip_runtime.h>

typedef unsigned int u32;
typedef unsigned short u16;
typedef _Float16 f16;
typedef _Float16 f16x2 __attribute__((ext_vector_type(2)));
typedef _Float16 f16x4 __attribute__((ext_vector_type(4)));

#define T_SEQ 32768

// ---------------- ws layout (bytes) ----------------
static const size_t OFF_DT   = 0;         // u32 dtype flag (1 = f32 inputs)
static const size_t OFF_FLG  = 1024;      // u32[128] (legacy, kept zeroed)
static const size_t OFF_MAP  = 4096;      // int [T]
static const size_t OFF_H1G  = 135168;    // f16 [1024][512]
static const size_t OFF_BIAS = 1183744;   // f32 [4][1024]
static const size_t OFF_FCW  = 1200128;   // f32 [512*64]
static const size_t OFF_WQ8  = 1331200;   // u32 [4][1024][64] int8 W_hh (1 MB)
static const size_t OFF_WIH0 = 3428352;   // u32 [2][1024][32]
static const size_t OFF_WIH1 = 3690496;   // u32 [2][1024][256]
static const size_t OFF_XQ   = 5787648;   // u32 [T][32]
static const size_t OFF_H0   = 9981952;   // f16 [T][512]
static const size_t OFF_XG   = 43536384;  // f16 xgT [ndir][1024][T], LAST
static const size_t XG_DIR   = (size_t)T_SEQ * 1024 * 2;  // 67108864 bytes
static const size_t NEED_PAR = OFF_XG + 2 * XG_DIR;       // 177754112

// ---------------- helpers ----------------
__device__ __forceinline__ float bf2f(u16 u) {
  union { u32 i; float f; } v; v.i = ((u32)u) << 16; return v.f;
}
__device__ __forceinline__ u16 f2bf(float f) {
  union { float f; u32 i; } v; v.f = f;
  u32 u = v.i;
  return (u16)((u + 0x7fffu + ((u >> 16) & 1u)) >> 16);
}
__device__ __forceinline__ u32 packf2(float a, float b) {
  f16x2 p; p.x = (f16)a; p.y = (f16)b;
  return __builtin_bit_cast(u32, p);
}
__device__ __forceinline__ u32 bf2f2(u32 v) {  // two bf16 -> two f16
  union { u32 i; float f; } lo, hi;
  lo.i = v << 16; hi.i = v & 0xffff0000u;
  return packf2(lo.f, hi.f);
}
__device__ __forceinline__ float ldf(const void* p, size_t i, u32 isf) {
  return isf ? ((const float*)p)[i] : bf2f(((const u16*)p)[i]);
}
__device__ __forceinline__ float fdot2f(f16x2 a, f16x2 b, float c) {
#if __has_builtin(__builtin_amdgcn_fdot2)
  return __builtin_amdgcn_fdot2(a, b, c, false);
#else
  return c + (float)a.x * (float)b.x + (float)a.y * (float)b.y;
#endif
}
__device__ __forceinline__ float fdotu(u32 a, u32 b, float c) {
  return fdot2f(__builtin_bit_cast(f16x2, a), __builtin_bit_cast(f16x2, b), c);
}
__device__ __forceinline__ int sdot4(u32 a, u32 b, int c) {
#if __has_builtin(__builtin_amdgcn_sdot4)
  return __builtin_amdgcn_sdot4((int)a, (int)b, c, false);
#else
  int r = c;
#pragma unroll
  for (int j = 0; j < 4; ++j)
    r += (int)(signed char)(a >> (8 * j)) * (int)(signed char)(b >> (8 * j));
  return r;
#endif
}
// quad lane permutes via DPP — pure VALU, no LDS pipe.
__device__ __forceinline__ int dpp_xor1(int x) {  // quad_perm [1,0,3,2]
#if __has_builtin(__builtin_amdgcn_update_dpp)
  return __builtin_amdgcn_update_dpp(0, x, 0xB1, 0xF, 0xF, true);
#else
  return __shfl_xor(x, 1);
#endif
}
__device__ __forceinline__ int dpp_xor2(int x) {  // quad_perm [2,3,0,1]
#if __has_builtin(__builtin_amdgcn_update_dpp)
  return __builtin_amdgcn_update_dpp(0, x, 0x4E, 0xF, 0xF, true);
#else
  return __shfl_xor(x, 2);
#endif
}
template <int CTRL>
__device__ __forceinline__ float dpp_bcastf(float x) {  // quad broadcast
#if __has_builtin(__builtin_amdgcn_update_dpp)
  return __builtin_bit_cast(float,
      __builtin_amdgcn_update_dpp(0, __builtin_bit_cast(int, x), CTRL, 0xF, 0xF, true));
#else
  return __shfl(x, (threadIdx.x & ~3) + (CTRL & 3));
#endif
}
__device__ __forceinline__ float sigf(float x) {
  return __builtin_amdgcn_rcpf(1.0f + __builtin_amdgcn_exp2f(-1.4426950408889634f * x));
}
__device__ __forceinline__ float tanhf_fast(float x) {
  return 1.0f - 2.0f * __builtin_amdgcn_rcpf(1.0f + __builtin_amdgcn_exp2f(2.8853900817779268f * x));
}
// raw workgroup barrier WITHOUT the vmcnt(0) drain __syncthreads imposes:
// only LDS (lgkmcnt) ordering is needed for the h-byte exchange; global
// loads/stores stay in flight across the barrier.
__device__ __forceinline__ void wg_barrier_lds() {
  asm volatile("s_waitcnt lgkmcnt(0)" ::: "memory");
  __builtin_amdgcn_s_barrier();
  asm volatile("" ::: "memory");
}

// ---------------- dtype detection ----------------
__global__ void k_detect(const u16* __restrict__ probe, u32* __restrict__ dt) {
  __shared__ int cnt;
  if (threadIdx.x == 0) cnt = 0;
  __syncthreads();
  int bad = 0;
  for (int i = threadIdx.x; i < 8192; i += 256) {
    float v = bf2f(probe[i]);
    if (!(v * v <= 16.0f)) bad++;
  }
  atomicAdd(&cnt, bad);
  __syncthreads();
  if (threadIdx.x == 0) *dt = (cnt > 64) ? 1u : 0u;
}

// ---------------- conversions ----------------
__global__ void k_conv_pairs(const void* __restrict__ src, u32* __restrict__ dst,
                             int np, const u32* __restrict__ dtp) {
  u32 isf = *dtp;
  int i = blockIdx.x * 256 + threadIdx.x;
  if (i >= np) return;
  if (isf) {
    const float* s = (const float*)src;
    dst[i] = packf2(s[2 * i], s[2 * i + 1]);
  } else {
    dst[i] = bf2f2(((const u32*)src)[i]);
  }
}

// int8-quantize one W_hh matrix [1024][256] -> u32 [1024][64], scale 2048
__global__ void k_quant(const void* __restrict__ src, u32* __restrict__ dst,
                        const u32* __restrict__ dtp) {
  u32 isf = *dtp;
  int i = blockIdx.x * 256 + threadIdx.x;  // 65536
  int row = i >> 6, c = i & 63;
  u32 out = 0;
#pragma unroll
  for (int j = 0; j < 4; ++j) {
    float w = ldf(src, (size_t)row * 256 + 4 * c + j, isf);
    int q = (int)rintf(w * 2048.0f);
    q = q > 127 ? 127 : (q < -127 ? -127 : q);
    out |= ((u32)(q & 0xff)) << (8 * j);
  }
  dst[i] = out;
}

__global__ void k_conv_misc(const void* bi0f, const void* bh0f, const void* bi0b, const void* bh0b,
                            const void* bi1f, const void* bh1f, const void* bi1b, const void* bh1b,
                            const void* fcb, float* __restrict__ bias, float* __restrict__ fcw,
                            u32* __restrict__ flags, int* __restrict__ map,
                            const u32* __restrict__ dtp) {
  u32 isf = *dtp;
  int i = blockIdx.x * 256 + threadIdx.x;
  if (i < 4096) {
    int ld = i >> 10, r = i & 1023;
    const void* bi; const void* bh;
    if (ld == 0)      { bi = bi0f; bh = bh0f; }
    else if (ld == 1) { bi = bi0b; bh = bh0b; }
    else if (ld == 2) { bi = bi1f; bh = bh1f; }
    else              { bi = bi1b; bh = bh1b; }
    bias[i] = ldf(bi, r, isf) + ldf(bh, r, isf);
  } else if (i < 36864) {
    fcw[i - 4096] = ldf(fcb, i - 4096, isf);
  } else if (i < 36992) {
    flags[i - 36864] = 0;
  } else if (i < 69760) {
    map[i - 36992] = -1;
  }
}

__global__ void k_conv_x(const void* __restrict__ Y, const void* __restrict__ dT,
                         u32* __restrict__ xq, const u32* __restrict__ dtp) {
  u32 isf = *dtp;
  int i = blockIdx.x * 256 + threadIdx.x;  // T*32
  if (i >= T_SEQ * 32) return;
  int t = i >> 5, m = i & 31, k2 = 2 * m;
  float a = ldf(Y, (size_t)t * 63 + k2, isf);
  float b = (k2 + 1 < 63) ? ldf(Y, (size_t)t * 63 + k2 + 1, isf) : ldf(dT, t, isf);
  xq[i] = packf2(a, b);
}

__global__ void k_map_set(const int* __restrict__ idx, int* __restrict__ map) {
  int i = blockIdx.x * 256 + threadIdx.x;
  if (i < 1024) map[idx[i]] = i;
}

// ---------------- input-projection GEMM ----------------
// Writes xg TRANSPOSED: xgT[row r][time t], with t-REVERSED storage when
// rev=1 so the recurrence always streams ascending addresses.
__global__ __launch_bounds__(256) void k_gemm(
    const u32* __restrict__ Aq, const u32* __restrict__ Wc,
    const float* __restrict__ bias, f16* __restrict__ xgT, int Kp, int rev) {
  int t0 = blockIdx.x << 6, r0 = blockIdx.y << 6;
  int tid = threadIdx.x, tx = tid & 15, ty = tid >> 4;
  __shared__ u32 As[64][33];
  __shared__ u32 Bs[64][33];
  float acc[4][4] = {};
  for (int kp0 = 0; kp0 < Kp; kp0 += 32) {
#pragma unroll
    for (int i = 0; i < 8; ++i) {
      int idx = tid + (i << 8);
      int row = idx >> 5, kp = idx & 31, kpg = kp0 + kp;
      As[row][kp] = Aq[(size_t)(t0 + row) * Kp + kpg];
      Bs[row][kp] = Wc[(size_t)(r0 + row) * Kp + kpg];
    }
    __syncthreads();
#pragma unroll 4
    for (int kk = 0; kk < 32; ++kk) {
      u32 av[4], bv[4];
#pragma unroll
      for (int i = 0; i < 4; ++i) av[i] = As[ty * 4 + i][kk];
#pragma unroll
      for (int i = 0; i < 4; ++i) bv[i] = Bs[tx * 4 + i][kk];
#pragma unroll
      for (int i = 0; i < 4; ++i)
#pragma unroll
        for (int j = 0; j < 4; ++j)
          acc[i][j] = fdotu(av[i], bv[j], acc[i][j]);
    }
    __syncthreads();
  }
  int tb = t0 + (ty << 2);
#pragma unroll
  for (int j = 0; j < 4; ++j) {
    int rr = r0 + tx * 4 + j;
    float b = bias[rr];
    f16 v0 = (f16)(acc[0][j] + b);
    f16 v1 = (f16)(acc[1][j] + b);
    f16 v2 = (f16)(acc[2][j] + b);
    f16 v3 = (f16)(acc[3][j] + b);
    size_t base = (size_t)rr * T_SEQ;
    f16x4 v;
    size_t pos;
    if (rev) { pos = base + (size_t)(T_SEQ - 4 - tb); v = (f16x4){v3, v2, v1, v0}; }
    else     { pos = base + (size_t)tb;               v = (f16x4){v0, v1, v2, v3}; }
    *(f16x4*)(xgT + pos) = v;
  }
}

// ---------------- recurrence v3 ------------------------------------------
// 1024 threads. Thread = (unit u = tid>>2, quarter qq = tid&3): owns all 4
// gate rows of unit u over K in [64*qq, 64*qq+64)  (64 sdot4/thread —
// per-SIMD issue floor 512 cyc, invariant).
// Key changes vs round 2 (which measured ~2400 cyc/step):
//  1. RAW s_barrier (lgkmcnt-only wait). __syncthreads emitted
//     s_waitcnt vmcnt(0) before s_barrier, so each step waited for next
//     step's xg prefetch to land from HBM/L2 (~800 cyc/step on the
//     critical path). Global ops now fly across barriers.
//  2. xg is stored transposed [1024][T] (t-reversed for dir=1): one uint4
//     load per thread per 8 steps, consumed a chunk later => fully hidden.
//  3. Gate-per-lane activation: quad transpose-reduce (exact integer
//     cndmask+DPP adds) leaves lane qq with gate qq's full-K sum; one
//     parametric nonlinearity per lane (bit-identical to sigf/tanhf_fast),
//     then 4 DPP quad-broadcasts rebuild {gi,gf,gg,go} in every lane.
//     Transcendentals drop 10 -> 4 per thread per step.
__global__ __launch_bounds__(1024, 4) void k_recur2(
    const f16* __restrict__ xgT, const u32* __restrict__ wq,
    f16* __restrict__ h_full, f16* __restrict__ h1g,
    const int* __restrict__ map, int dir0) {
  const int dir = dir0 + blockIdx.x;
  const int tid = threadIdx.x;
  const int u = tid >> 2;    // hidden unit owned by this quad
  const int qq = tid & 3;    // K quarter / gate lane
  const u32* wqd = wq + ((size_t)dir << 16);  // [1024][64]

  __shared__ __align__(16) unsigned char hb8[2][256];  // double-buffered h (i8)

  u32 w0[16], w1[16], w2[16], w3[16];
  {
    const uint4* pw = (const uint4*)wqd;  // row stride = 16 uint4
    const int b0 = ((0 << 8) | u) * 16 + (qq << 2);
    const int b1 = ((1 << 8) | u) * 16 + (qq << 2);
    const int b2 = ((2 << 8) | u) * 16 + (qq << 2);
    const int b3 = ((3 << 8) | u) * 16 + (qq << 2);
#pragma unroll
    for (int i = 0; i < 4; ++i) {
      uint4 v0 = pw[b0 + i]; uint4 v1 = pw[b1 + i];
      uint4 v2 = pw[b2 + i]; uint4 v3 = pw[b3 + i];
      w0[4 * i] = v0.x; w0[4 * i + 1] = v0.y; w0[4 * i + 2] = v0.z; w0[4 * i + 3] = v0.w;
      w1[4 * i] = v1.x; w1[4 * i + 1] = v1.y; w1[4 * i + 2] = v1.z; w1[4 * i + 3] = v1.w;
      w2[4 * i] = v2.x; w2[4 * i + 1] = v2.y; w2[4 * i + 2] = v2.z; w2[4 * i + 3] = v2.w;
      w3[4 * i] = v3.x; w3[4 * i + 1] = v3.y; w3[4 * i + 2] = v3.z; w3[4 * i + 3] = v3.w;
    }
  }

  if (tid < 128) ((u32*)hb8)[tid] = 0;

  const float ksc = 1.0f / (2048.0f * 127.0f);
  // per-lane activation params: sigmoid for gates i,f,o; tanh for gate g(=2)
  // sigmoid(x) = rcp(1+exp2(-1.4427x));  tanh(x) = 1 - 2*rcp(1+exp2(2.8854x))
  const float sk = (qq == 2) ? 2.8853900817779268f : -1.4426950408889634f;
  const float aa = (qq == 2) ? -2.0f : 1.0f;
  const float bb = (qq == 2) ? 1.0f : 0.0f;

  const f16* xg_d = xgT + (size_t)blockIdx.x * ((size_t)T_SEQ * 1024);
  const f16* xrow = xg_d + (size_t)((qq << 8) | u) * T_SEQ;  // own gate row

  const int tstep = dir ? -1 : 1;
  int t = dir ? (T_SEQ - 1) : 0;
  int mp = map ? map[t] : -1;
  float c_state = 0.f;

  uint4 xcur = *(const uint4*)xrow;  // steps 0..7 of own gate
  uint4 xnxt = xcur;

  __syncthreads();  // hb8 zero visible (full drain once, outside the loop)

  for (int ch = 0; ch < T_SEQ / 8; ++ch) {
    if (ch + 1 < T_SEQ / 8) xnxt = *(const uint4*)(xrow + (((size_t)ch + 1) << 3));
#pragma unroll
    for (int j = 0; j < 8; ++j) {
      // own-gate pre-activation input for this step (static extract)
      u32 dw = (j >> 1) == 0 ? xcur.x : (j >> 1) == 1 ? xcur.y
             : (j >> 1) == 2 ? xcur.z : xcur.w;
      f16x2 pr = __builtin_bit_cast(f16x2, dw);
      float xb = (float)((j & 1) ? pr.y : pr.x);

      int ms = mp;
      if (map) {  // prefetch next map slot (uniform, hidden under the step)
        int tn = t + tstep;
        int idx2 = ((unsigned)tn < T_SEQ) ? tn : t;
        mp = map[idx2];
      }

      const uint4* hp = (const uint4*)(&hb8[j & 1][qq << 6]);
      uint4 hv0 = hp[0], hv1 = hp[1], hv2 = hp[2], hv3 = hp[3];
      int acc0 = 0, acc1 = 0, acc2 = 0, acc3 = 0;
#define DOT4Q(HV, K)                 \
      acc0 = sdot4(w0[K], HV, acc0); \
      acc1 = sdot4(w1[K], HV, acc1); \
      acc2 = sdot4(w2[K], HV, acc2); \
      acc3 = sdot4(w3[K], HV, acc3);
      DOT4Q(hv0.x, 0)  DOT4Q(hv0.y, 1)  DOT4Q(hv0.z, 2)  DOT4Q(hv0.w, 3)
      DOT4Q(hv1.x, 4)  DOT4Q(hv1.y, 5)  DOT4Q(hv1.z, 6)  DOT4Q(hv1.w, 7)
      DOT4Q(hv2.x, 8)  DOT4Q(hv2.y, 9)  DOT4Q(hv2.z, 10) DOT4Q(hv2.w, 11)
      DOT4Q(hv3.x, 12) DOT4Q(hv3.y, 13) DOT4Q(hv3.z, 14) DOT4Q(hv3.w, 15)
#undef DOT4Q
      // quad transpose-reduce: lane qq ends with gate qq's FULL-K sum
      // (exact integer adds -> bit-identical to the unsplit dot)
      int A = (qq & 1) ? acc1 : acc0;
      int B = (qq & 1) ? acc0 : acc1;
      A += dpp_xor1(B);
      int C = (qq & 1) ? acc3 : acc2;
      int D = (qq & 1) ? acc2 : acc3;
      C += dpp_xor1(D);
      int E = (qq & 2) ? C : A;
      int F = (qq & 2) ? A : C;
      E += dpp_xor2(F);

      float x = __builtin_fmaf((float)E, ksc, xb);
      float r = __builtin_amdgcn_rcpf(1.0f + __builtin_amdgcn_exp2f(sk * x));
      float g = __builtin_fmaf(aa, r, bb);  // own activated gate
      float gi = dpp_bcastf<0x00>(g);
      float gf = dpp_bcastf<0x55>(g);
      float gg = dpp_bcastf<0xAA>(g);
      float go = dpp_bcastf<0xFF>(g);
      c_state = __builtin_fmaf(gf, c_state, gi * gg);
      float h = go * tanhf_fast(c_state);
      int q8 = (int)rintf(h * 127.0f);
      if (qq == 0) {
        hb8[(j & 1) ^ 1][u] = (unsigned char)(q8 & 0xff);
        if (h_full) h_full[(size_t)t * 512 + (dir << 8) + u] = (f16)h;
        if (h1g && ms >= 0) h1g[(size_t)ms * 512 + (dir << 8) + u] = (f16)h;
      }
      wg_barrier_lds();  // LDS-only wait; global ops stay in flight
      t += tstep;
    }
    xcur = xnxt;
  }
}

// ---------------- FC + gather ----------------
__global__ void k_fc(const f16* __restrict__ h1g, const int* __restrict__ map,
                     const int* __restrict__ idx, const float* __restrict__ fcw,
                     void* __restrict__ out, const u32* __restrict__ dtp) {
  u32 isf = *dtp;
  int n = blockIdx.x;
  int cc = threadIdx.x;  // 64
  int slot = map[idx[n]];
  const f16* hp = h1g + (size_t)slot * 512;
  float acc = 0.f;
#pragma unroll 8
  for (int k = 0; k < 512; ++k) acc += (float)hp[k] * fcw[k * 64 + cc];
  int o = (cc < 32) ? (n * 32 + cc) : (32 * 1024 + n * 32 + (cc - 32));
  if (isf) ((float*)out)[o] = acc;
  else     ((u16*)out)[o]   = f2bf(acc);
}

// ---------------- launch ----------------
extern "C" void kernel_launch(void* const* d_in, const int* in_sizes, int n_in,
                              void* d_out, int out_size, void* d_ws, size_t ws_size,
                              hipStream_t stream) {
  const void* Y        = d_in[0];
  const void* dT       = d_in[1];
  const int*  idx      = (const int*)d_in[2];
  const void* w_ih_l0f = d_in[3];
  const void* w_hh_l0f = d_in[4];
  const void* b_ih_l0f = d_in[5];
  const void* b_hh_l0f = d_in[6];
  const void* w_ih_l0b = d_in[7];
  const void* w_hh_l0b = d_in[8];
  const void* b_ih_l0b = d_in[9];
  const void* b_hh_l0b = d_in[10];
  const void* w_ih_l1f = d_in[11];
  const void* w_hh_l1f = d_in[12];
  const void* b_ih_l1f = d_in[13];
  const void* b_hh_l1f = d_in[14];
  const void* w_ih_l1b = d_in[15];
  const void* w_hh_l1b = d_in[16];
  const void* b_ih_l1b = d_in[17];
  const void* b_hh_l1b = d_in[18];
  const void* fcbf     = d_in[19];

  char* ws = (char*)d_ws;
  u32*  dt    = (u32*)(ws + OFF_DT);
  u32*  flags = (u32*)(ws + OFF_FLG);
  int*  map   = (int*)(ws + OFF_MAP);
  f16*  h1g   = (f16*)(ws + OFF_H1G);
  float* bias = (float*)(ws + OFF_BIAS);
  float* fcw  = (float*)(ws + OFF_FCW);
  u32*  wq8   = (u32*)(ws + OFF_WQ8);
  u32*  wih0  = (u32*)(ws + OFF_WIH0);
  u32*  wih1  = (u32*)(ws + OFF_WIH1);
  u32*  xq    = (u32*)(ws + OFF_XQ);
  f16*  h0    = (f16*)(ws + OFF_H0);
  f16*  xg    = (f16*)(ws + OFF_XG);
  f16*  xg1   = xg + XG_DIR / 2;  // f16 elements

  const int par = (ws_size >= NEED_PAR) ? 1 : 0;

  k_detect<<<1, 256, 0, stream>>>((const u16*)w_hh_l0f, dt);
  k_quant<<<256, 256, 0, stream>>>(w_hh_l0f, wq8 + 0 * 65536, dt);
  k_quant<<<256, 256, 0, stream>>>(w_hh_l0b, wq8 + 1 * 65536, dt);
  k_quant<<<256, 256, 0, stream>>>(w_hh_l1f, wq8 + 2 * 65536, dt);
  k_quant<<<256, 256, 0, stream>>>(w_hh_l1b, wq8 + 3 * 65536, dt);
  k_conv_pairs<<<128, 256, 0, stream>>>(w_ih_l0f, wih0 + 0, 32768, dt);
  k_conv_pairs<<<128, 256, 0, stream>>>(w_ih_l0b, wih0 + 32768, 32768, dt);
  k_conv_pairs<<<1024, 256, 0, stream>>>(w_ih_l1f, wih1 + 0, 262144, dt);
  k_conv_pairs<<<1024, 256, 0, stream>>>(w_ih_l1b, wih1 + 262144, 262144, dt);
  k_conv_misc<<<273, 256, 0, stream>>>(b_ih_l0f, b_hh_l0f, b_ih_l0b, b_hh_l0b,
                                       b_ih_l1f, b_hh_l1f, b_ih_l1b, b_hh_l1b,
                                       fcbf, bias, fcw, flags, map, dt);
  k_conv_x<<<4096, 256, 0, stream>>>(Y, dT, xq, dt);
  k_map_set<<<4, 256, 0, stream>>>(idx, map);

  dim3 ggrid(T_SEQ / 64, 16);
  if (par) {
    k_gemm<<<ggrid, 256, 0, stream>>>(xq, wih0, bias, xg, 32, 0);
    k_gemm<<<ggrid, 256, 0, stream>>>(xq, wih0 + 32768, bias + 1024, xg1, 32, 1);
    k_recur2<<<2, 1024, 0, stream>>>(xg, wq8, h0, nullptr, nullptr, 0);
    k_gemm<<<ggrid, 256, 0, stream>>>((const u32*)h0, wih1, bias + 2048, xg, 256, 0);
    k_gemm<<<ggrid, 256, 0, stream>>>((const u32*)h0, wih1 + 262144, bias + 3072, xg1, 256, 1);
    k_recur2<<<2, 1024, 0, stream>>>(xg, wq8 + 2 * 65536, nullptr, h1g, map, 0);
  } else {
    k_gemm<<<ggrid, 256, 0, stream>>>(xq, wih0, bias, xg, 32, 0);
    k_recur2<<<1, 1024, 0, stream>>>(xg, wq8, h0, nullptr, nullptr, 0);
    k_gemm<<<ggrid, 256, 0, stream>>>(xq, wih0 + 32768, bias + 1024, xg, 32, 1);
    k_recur2<<<1, 1024, 0, stream>>>(xg, wq8, h0, nullptr, nullptr, 1);
    k_gemm<<<ggrid, 256, 0, stream>>>((const u32*)h0, wih1, bias + 2048, xg, 256, 0);
    k_recur2<<<1, 1024, 0, stream>>>(xg, wq8 + 2 * 65536, nullptr, h1g, map, 0);
    k_gemm<<<ggrid, 256, 0, stream>>>((const u32*)h0, wih1 + 262144, bias + 3072, xg, 256, 1);
    k_recur2<<<1, 1024, 0, stream>>>(xg, wq8 + 2 * 65536, nullptr, h1g, map, 1);
  }
  k_fc<<<1024, 64, 0, stream>>>(h1g, map, idx, fcw, d_out, dt);
}